// Round 5
// baseline (369.644 us; speedup 1.0000x reference)
//
#include <hip/hip_runtime.h>

#define T_LEN   65536
#define P       64
#define BASE    4096           // base length produced by the in-block ladder
#define W_TILE  1024
#define BCHUNK  8

typedef float f4 __attribute__((ext_vector_type(4)));

// ---------------------------------------------------------------------------
// means[t] = bias * R[t], R = step response of the AR(64) filter:
//   R[t] = sum_k params[k]*R[t-1-k] + 1,  R[t<0] = 0
// Extension identity (valid for any tau in [0, L)):
//   R[L+tau] = R[tau] + sum_{i=0}^{64} V_L[i]*R[tau-i]
// R10: SINGLE kernel, 2048 independent blocks. The R7 serial ar_k1 (45 us,
// latency-bound on one CU) is eliminated: every block recomputes the
// ladder + its own V_k chain privately in LDS (~420K fma, chip-total 11 us
// of VALU, fully parallel), with its noise rows prefetched into registers
// FIRST so the HBM read latency hides under the ladder. Arithmetic is
// order-identical to R7 (tap partials/summation, boundary, convs), so
// absmax must be bitwise-unchanged. tap+reduce fused into one wave via
// __shfl_up (same partial sums, same add order -> bit-identical V).
// ---------------------------------------------------------------------------

// per-k ancestor chains (same node defs as the R7 tree, linearized):
// k=2:D192 | 3:+A256 | 4:D192,D128 | 5:+A256 | 6:D192,A256,D192 | 7:+A256
// 8:D192,D128,D64 | 9:+A256 | 10:D192,D128,A256,D192 | 11:+A256
// 12:D192,A256,D192,D128 | 13:+A256 | 14:D192,A256,D192,A256,D192 | 15:+A256
__constant__ unsigned char CH_N[16] = {0,0,1,2,2,3,3,4,3,4,4,5,4,5,5,6};
__constant__ unsigned char CH_DBL[16][6] = {
  {0,0,0,0,0,0},{0,0,0,0,0,0},
  {1,0,0,0,0,0},{1,0,0,0,0,0},
  {1,1,0,0,0,0},{1,1,0,0,0,0},
  {1,0,1,0,0,0},{1,0,1,0,0,0},
  {1,1,1,0,0,0},{1,1,1,0,0,0},
  {1,1,0,1,0,0},{1,1,0,1,0,0},
  {1,0,1,1,0,0},{1,0,1,1,0,0},
  {1,0,1,0,1,0},{1,0,1,0,1,0},
};
__constant__ unsigned short CH_W[16][6] = {
  {0,0,0,0,0,0},{0,0,0,0,0,0},
  {192,0,0,0,0,0},{192,256,0,0,0,0},
  {192,128,0,0,0,0},{192,128,256,0,0,0},
  {192,256,192,0,0,0},{192,256,192,256,0,0},
  {192,128,64,0,0,0},{192,128,64,256,0,0},
  {192,128,256,192,0,0},{192,128,256,192,256,0},
  {192,256,192,128,0,0},{192,256,192,128,256,0},
  {192,256,192,256,192,0},{192,256,192,256,192,256},
};

// Fused tap+reduce: lane j computes the four 16-wide partials of W0[j] in the
// SAME order as R7's (j,c) threads, sums them left-assoc (bit-identical),
// then V[j] = W0[j]-W0[j-1] via shfl_up. Lane 63 also writes V[64] = -W0[63].
__device__ __forceinline__ void tapV(const float* __restrict__ td, int wd,
                                     const float* __restrict__ p,
                                     float* __restrict__ Vdst, int tid) {
    if (tid < 64) {
        const int j = tid;
        float w0 = 0.f, w1 = 0.f, w2 = 0.f, w3 = 0.f;
        #pragma unroll
        for (int mm = 0; mm < 16; ++mm) w0 = fmaf(p[mm + j],      td[wd - 1  - mm], w0);
        #pragma unroll
        for (int mm = 0; mm < 16; ++mm) w1 = fmaf(p[16 + mm + j], td[wd - 17 - mm], w1);
        #pragma unroll
        for (int mm = 0; mm < 16; ++mm) w2 = fmaf(p[32 + mm + j], td[wd - 33 - mm], w2);
        #pragma unroll
        for (int mm = 0; mm < 16; ++mm) w3 = fmaf(p[48 + mm + j], td[wd - 49 - mm], w3);
        const float wj  = ((w0 + w1) + w2) + w3;
        const float wm1 = __shfl_up(wj, 1);
        Vdst[j] = (j == 0) ? wj : (wj - wm1);
        if (j == 63) Vdst[64] = 0.0f - wj;
    }
}

__global__ __launch_bounds__(256) void ar_all(const float* __restrict__ params,
                                              const float* __restrict__ bias,
                                              const float* __restrict__ noise,
                                              float* __restrict__ out) {
    __shared__ __align__(16) float Rl[BASE];
    __shared__ float p[128];          // zero-padded: p[64..127] = 0 masks m+j>63
    __shared__ __align__(16) float Va[68];
    __shared__ __align__(16) float Vb[68];
    __shared__ __align__(16) float Ta[256];
    __shared__ __align__(16) float Tb[256];

    const int tid  = threadIdx.x;
    const int tile = blockIdx.x & 63;           // 64 tiles of 1024
    const int bc   = blockIdx.x >> 6;           // 32 chunks of 8 rows
    const int t0   = tile * W_TILE;
    const int k    = t0 >> 12;                  // 0..15
    const int tau0 = t0 & 4095;
    const int nb4  = T_LEN >> 2;
    const int col  = (t0 >> 2) + tid;
    const int row0 = bc * BCHUNK;
    const f4* __restrict__ n4 = reinterpret_cast<const f4*>(noise);
    f4* __restrict__ o4 = reinterpret_cast<f4*>(out);

    // ---- prefetch this block's 8 noise rows FIRST: HBM latency hides under
    //      the in-LDS ladder below (no use until the final stream-out) ----
    f4 nf[BCHUNK];
    #pragma unroll
    for (int r = 0; r < BCHUNK; ++r)
        nf[r] = __builtin_nontemporal_load(n4 + (row0 + r) * nb4 + col);

    const float b = bias[0];

    if (tid < 128) p[tid] = (tid < P) ? params[tid] : 0.f;
    __syncthreads();

    // ---- serial stage: lane t holds transposed-form state (verbatim) ----
    if (tid < 64) {
        float z = 0.f;
        const float pk = p[tid];
        #pragma unroll 1
        for (int t = 0; t < 64; ++t) {
            float y  = __shfl(z, 0) + 1.0f;   // R[t]
            float zn = __shfl_down(z, 1);
            if (tid == 63) zn = 0.f;
            z = fmaf(pk, y, zn);
            if (tid == 0) Rl[t] = y;
        }
    }
    __syncthreads();

    // ---- ladder 64 -> 4096 in LDS: 2 stages/level (fused tapV, then
    //      boundary + blocked conv — both verbatim R7 arithmetic) ----
    #pragma unroll 1
    for (int L = 64; L <= BASE / 2; L <<= 1) {
        tapV(Rl, L, p, Va, tid);
        __syncthreads();
        if (tid < P) {                          // boundary tau in [0,64)
            const int tau = tid;
            float acc = Rl[tau];
            #pragma unroll
            for (int i = 0; i < P; ++i) {
                const int idx = (tau - i) > 0 ? (tau - i) : 0;
                const float v = (i <= tau) ? Va[i] : 0.f;
                acc = fmaf(v, Rl[idx], acc);
            }
            Rl[L + tau] = acc;
        }
        {                                       // blocked tau in [64,L)
            const f4* __restrict__ Rl4 = reinterpret_cast<const f4*>(Rl);
            f4* __restrict__ Rl4w = reinterpret_cast<f4*>(Rl);
            const f4* __restrict__ V4 = reinterpret_cast<const f4*>(Va);
            const int nq = (L - 64) >> 2;
            #pragma unroll 1
            for (int q = tid; q < nq; q += 256) {
                f4 w4[17];
                #pragma unroll
                for (int j = 0; j < 17; ++j) w4[j] = Rl4[q + j];
                float a0 = w4[16].x, a1 = w4[16].y, a2 = w4[16].z, a3 = w4[16].w;
                #pragma unroll
                for (int g = 0; g < 16; ++g) {   // i = 4g..4g+3
                    const f4 v  = V4[g];
                    const f4 hi = w4[16 - g];
                    const f4 lo = w4[15 - g];
                    a0 = fmaf(v.x, hi.x, a0); a1 = fmaf(v.x, hi.y, a1);
                    a2 = fmaf(v.x, hi.z, a2); a3 = fmaf(v.x, hi.w, a3);
                    a0 = fmaf(v.y, lo.w, a0); a1 = fmaf(v.y, hi.x, a1);
                    a2 = fmaf(v.y, hi.y, a2); a3 = fmaf(v.y, hi.z, a3);
                    a0 = fmaf(v.z, lo.z, a0); a1 = fmaf(v.z, lo.w, a1);
                    a2 = fmaf(v.z, hi.x, a2); a3 = fmaf(v.z, hi.y, a3);
                    a0 = fmaf(v.w, lo.y, a0); a1 = fmaf(v.w, lo.z, a1);
                    a2 = fmaf(v.w, lo.w, a2); a3 = fmaf(v.w, hi.x, a3);
                }
                const float v64 = Va[64];
                a0 = fmaf(v64, w4[0].x, a0); a1 = fmaf(v64, w4[0].y, a1);
                a2 = fmaf(v64, w4[0].z, a2); a3 = fmaf(v64, w4[0].w, a3);
                f4 o; o.x = a0; o.y = a1; o.z = a2; o.w = a3;
                Rl4w[((L + 64) >> 2) + q] = o;
            }
        }
        __syncthreads();
    }

    // ---- this block's V_k chain (only its own ancestors, <=6 steps).
    //      Node defs/arithmetic identical to the R7 tree; tails ping-pong. ----
    float* Vc = Va;
    if (k >= 1) {
        tapV(Rl + 3840, 256, p, Va, tid);       // node1: tail = R[3840..4096)
        __syncthreads();
        const float* Tp = Rl + 3840;            // prev tail (node1 lives in Rl)
        float* Tc = Ta;
        const int ns = CH_N[k];
        #pragma unroll 1
        for (int s = 0; s < ns; ++s) {
            const int wdn = (int)CH_W[k][s];
            const float* s0 = CH_DBL[k][s] ? (Tp + 64) : (Rl + 3840);
            if (tid < wdn) {                    // conv step (verbatim form)
                float acc = s0[tid];
                #pragma unroll
                for (int i = 0; i <= P; ++i)
                    acc = fmaf(Vc[i], s0[tid - i], acc);
                Tc[tid] = acc;
            }
            __syncthreads();
            float* Vn = (Vc == Va) ? Vb : Va;
            tapV(Tc, wdn, p, Vn, tid);
            __syncthreads();
            Vc = Vn; Tp = Tc; Tc = (Tc == Ta) ? Tb : Ta;
        }
    }

    // ---- epilogue conv (R7 ar_out math, window read straight from LDS) ----
    const f4* __restrict__ Rl4 = reinterpret_cast<const f4*>(Rl);
    f4 rt;
    if (k == 0) {
        const f4 r = Rl4[(t0 >> 2) + tid];
        rt.x = b * r.x; rt.y = b * r.y; rt.z = b * r.z; rt.w = b * r.w;
    } else {
        const int wb = ((tau0 - 64) >> 2) + tid;    // may be <0 only if tau0==0
        f4 w4[17];
        #pragma unroll
        for (int j = 0; j < 17; ++j) {
            const int ix = wb + j;
            f4 v;
            if (ix >= 0) v = Rl4[ix];
            else { v.x = 0.f; v.y = 0.f; v.z = 0.f; v.w = 0.f; }
            w4[j] = v;
        }
        const f4* __restrict__ V4 = reinterpret_cast<const f4*>(Vc);
        float a0 = w4[16].x, a1 = w4[16].y, a2 = w4[16].z, a3 = w4[16].w;
        #pragma unroll
        for (int g = 0; g < 16; ++g) {
            const f4 v  = V4[g];
            const f4 hi = w4[16 - g];
            const f4 lo = w4[15 - g];
            a0 = fmaf(v.x, hi.x, a0); a1 = fmaf(v.x, hi.y, a1);
            a2 = fmaf(v.x, hi.z, a2); a3 = fmaf(v.x, hi.w, a3);
            a0 = fmaf(v.y, lo.w, a0); a1 = fmaf(v.y, hi.x, a1);
            a2 = fmaf(v.y, hi.y, a2); a3 = fmaf(v.y, hi.z, a3);
            a0 = fmaf(v.z, lo.z, a0); a1 = fmaf(v.z, lo.w, a1);
            a2 = fmaf(v.z, hi.x, a2); a3 = fmaf(v.z, hi.y, a3);
            a0 = fmaf(v.w, lo.y, a0); a1 = fmaf(v.w, lo.z, a1);
            a2 = fmaf(v.w, lo.w, a2); a3 = fmaf(v.w, hi.x, a3);
        }
        const float v64 = Vc[64];
        a0 = fmaf(v64, w4[0].x, a0); a1 = fmaf(v64, w4[0].y, a1);
        a2 = fmaf(v64, w4[0].z, a2); a3 = fmaf(v64, w4[0].w, a3);
        rt.x = b * a0; rt.y = b * a1; rt.z = b * a2; rt.w = b * a3;
    }

    // ---- stream the 8 prefetched rows ----
    #pragma unroll
    for (int r = 0; r < BCHUNK; ++r) {
        const f4 n = nf[r];
        f4 o;
        o.x = fmaf(0.3f, n.x, rt.x);
        o.y = fmaf(0.3f, n.y, rt.y);
        o.z = fmaf(0.3f, n.z, rt.z);
        o.w = fmaf(0.3f, n.w, rt.w);
        __builtin_nontemporal_store(o, o4 + (row0 + r) * nb4 + col);
    }
}

extern "C" void kernel_launch(void* const* d_in, const int* in_sizes, int n_in,
                              void* d_out, int out_size, void* d_ws, size_t ws_size,
                              hipStream_t stream) {
    const float* params = (const float*)d_in[0];
    const float* bias   = (const float*)d_in[1];
    const float* noise  = (const float*)d_in[2];
    float* out = (float*)d_out;
    (void)d_ws; (void)ws_size;   // no workspace needed anymore

    hipLaunchKernelGGL(ar_all, dim3(64 * 32), dim3(256), 0, stream,
                       params, bias, noise, out);
}

// Round 6
// 246.427 us; speedup vs baseline: 1.5000x; 1.5000x over previous
//
#include <hip/hip_runtime.h>

#define T_LEN   65536
#define P       64
#define BASE    2048           // base length (k = t0>>11, tau0 in {0,1024})
#define K1_THREADS 256
#define W_TILE  1024
#define BCHUNK  8
#define VOFF    4096           // V_k published at R[VOFF + 80*k .. +64], k=1..31

typedef float f4 __attribute__((ext_vector_type(4)));

// ---------------------------------------------------------------------------
// means[t] = bias * R[t], R = step response of the AR(64) filter.
// Zero-padded R satisfies a homogeneous 65-tap recurrence for all t>=1:
//   R[t] = sum_{i=0..64} c1[i] R[t-1-i],
//   c1[0]=1+p0, c1[i]=p_i-p_{i-1} (1<=i<=63), c1[64]=-p63.
// Advance vectors are residues x^D mod m (m = char poly, deg 65) and COMPOSE
// AS POLYNOMIAL PRODUCTS. R11: ar_k1 replaces the doubling ladder + tap tree
// (a ~100K-cycle serialized LDS latency chain) with:
//   S1: wave0 serial R[0..64) (verbatim)  ||  wave1 builds T[j]=x^{65+j} mod m
//   S2: P_{64k'} = (x^64)^k' (x^64 exact), k'=1..32, 5 batched product stages
//       then G_k = P_{2048k}, k=1..31, 5 more product stages
//       (each product: 65x65 raw conv + parallel table-reduce, 2 barriers)
//   S3: convert residues to lag form (Cs_{k'} for base-fill, V_k to publish)
//   S4: base-fill R[64..2048) from R[0..64) via Cs convs; publish base + V.
// Epilogue kernel is R7-verbatim with BASE=2048 constants (window zero-pad
// at u<0 is exact: the 65-tap recurrence holds from t=1 with zero-padding).
// ---------------------------------------------------------------------------

// product schedule: slots 1..32 hold P_{64*s}; slot 32+k holds G_k (k>=2),
// G_1 = slot 32 (= P_2048). Each entry: dst = a*b (exponents add).
__constant__ unsigned char PRD_D[61] = {
   2,
   3, 4,
   5, 6, 7, 8,
   9,10,11,12,13,14,15,16,
  17,18,19,20,21,22,23,24,25,26,27,28,29,30,31,32,
  34,
  35,36,
  37,38,39,40,
  41,42,43,44,45,46,47,48,
  49,50,51,52,53,54,55,56,57,58,59,60,61,62,63
};
__constant__ unsigned char PRD_A[61] = {
   1,
   2, 2,
   3, 3, 4, 4,
   5, 5, 6, 6, 7, 7, 8, 8,
   9, 9,10,10,11,11,12,12,13,13,14,14,15,15,16,16,
  32,
  34,34,
  35,35,36,36,
  37,37,38,38,39,39,40,40,
  41,41,42,42,43,43,44,44,45,45,46,46,47,47,48
};
__constant__ unsigned char PRD_B[61] = {
   1,
   1, 2,
   2, 3, 3, 4,
   4, 5, 5, 6, 6, 7, 7, 8,
   8, 9, 9,10,10,11,11,12,12,13,13,14,14,15,15,16,
  32,
  32,34,
  34,35,35,36,
  36,37,37,38,38,39,39,40,
  40,41,41,42,42,43,43,44,44,45,45,46,46,47,47
};
__constant__ int STG[11] = {0,1,3,7,15,31,32,34,38,46,61};

__global__ __launch_bounds__(K1_THREADS, 1) void ar_k1(const float* __restrict__ params,
                                                       float* __restrict__ R) {
    __shared__ float p[128];                 // zero-padded params
    __shared__ __align__(16) float Rl[BASE];
    __shared__ float T[64][68];              // T[j] = x^{65+j} mod m
    __shared__ float PL[64][68];             // residue slots (65 coeffs each)
    __shared__ float rawb[16][132];          // raw products, max stage width 16
    __shared__ float Cs[32][68];             // lag-form for base-fill, k'=1..31
    const int tid = threadIdx.x;

    if (tid < 128) p[tid] = (tid < P) ? params[tid] : 0.f;
    if (tid < 68)  PL[1][tid] = (tid == 64) ? 1.f : 0.f;   // x^64 (exact)
    __syncthreads();

    // ---- S1: wave0 serial R[0..64)  ||  wave1 reduction-table build ----
    if (tid < 64) {
        float z = 0.f;
        const float pk = p[tid];
        #pragma unroll 1
        for (int t = 0; t < 64; ++t) {
            float y  = __shfl(z, 0) + 1.0f;   // R[t]
            float zn = __shfl_down(z, 1);
            if (tid == 63) zn = 0.f;
            z = fmaf(pk, y, zn);
            if (tid == 0) Rl[t] = y;
        }
    } else if (tid < 128) {
        // lane l holds coeff theta=l; hi = coeff theta=64 (replicated).
        // Mc = x^65 mod m: Mc[0]=-p63, Mc[th]=p[64-th]-p[63-th] (1..63), Mc[64]=1+p0
        const int l = tid - 64;
        const float mc   = (l == 0) ? -p[63] : (p[64 - l] - p[63 - l]);
        const float mc64 = 1.f + p[0];
        float cur = mc, hi = mc64;
        T[0][l] = cur; if (l == 0) T[0][64] = hi;
        #pragma unroll 1
        for (int j = 1; j < 64; ++j) {
            // x * T[j-1] mod m: new[th] = old[th-1] + old[64]*Mc[th]
            const float up  = __shfl_up(cur, 1);
            const float c63 = __shfl(cur, 63);
            const float ncur = fmaf(hi, mc, (l == 0) ? 0.f : up);
            hi  = fmaf(hi, mc64, c63);
            cur = ncur;
            T[j][l] = cur; if (l == 0) T[j][64] = hi;
        }
    }
    __syncthreads();

    // ---- S2: 10 batched product stages ----
    #pragma unroll 1
    for (int s = 0; s < 10; ++s) {
        const int off = STG[s];
        const int w   = STG[s + 1] - off;
        // phase 1: raw[d] = sum_{i+j=d} A[i]*B[j], d = 0..128
        #pragma unroll 1
        for (int idx = tid; idx < w * 129; idx += K1_THREADS) {
            const int pr = idx / 129, d = idx - pr * 129;
            const float* __restrict__ A = PL[PRD_A[off + pr]];
            const float* __restrict__ B = PL[PRD_B[off + pr]];
            float acc = 0.f;
            #pragma unroll
            for (int i = 0; i < 65; ++i) {
                const int j  = d - i;
                const int jc = j < 0 ? 0 : (j > 64 ? 64 : j);
                const float bv = (j == jc) ? B[jc] : 0.f;
                acc = fmaf(A[i], bv, acc);
            }
            rawb[pr][d] = acc;
        }
        __syncthreads();
        // phase 2: reduce degrees 65..128 via table
        #pragma unroll 1
        for (int idx = tid; idx < w * 65; idx += K1_THREADS) {
            const int pr = idx / 65, th = idx - pr * 65;
            float r = rawb[pr][th];
            #pragma unroll
            for (int j = 0; j < 64; ++j)
                r = fmaf(rawb[pr][65 + j], T[j][th], r);
            PL[PRD_D[off + pr]][th] = r;
        }
        __syncthreads();
    }

    // ---- S3: convert residues to lag form ----
    // lag C[i] = coeff of x^{64-i} in (x^64 * X mod m):
    //   C_poly[th] = (th==64)*X[0] + sum_j X[j+1]*T[j][th];  C[i]=C_poly[64-i]
    // rows 0..30: Cs_{k'} from PL[k'] (k'=1..31) -> LDS
    // rows 31..61: V_k from PL[32] (k=1) / PL[32+k] -> global (minus e0)
    #pragma unroll 1
    for (int idx = tid; idx < 62 * 65; idx += K1_THREADS) {
        const int row = idx / 65, th = idx - row * 65;
        const int isV = row >= 31;
        const int k   = isV ? (row - 30) : (row + 1);       // 1..31
        const float* __restrict__ X = PL[isV ? ((k == 1) ? 32 : 32 + k) : k];
        float cpo = (th == 64) ? X[0] : 0.f;
        #pragma unroll
        for (int j = 0; j < 64; ++j)
            cpo = fmaf(X[j + 1], T[j][th], cpo);
        const int i = 64 - th;
        if (isV) R[VOFF + 80 * k + i] = cpo - ((i == 0) ? 1.f : 0.f);
        else     Cs[k][i] = cpo;
    }
    __syncthreads();

    // ---- S4: base-fill R[64k'+x], k'=1..31, x in [0,64): window R[0..64) ----
    #pragma unroll 1
    for (int idx = tid; idx < 31 * 64; idx += K1_THREADS) {
        const int kp = 1 + (idx >> 6), x = idx & 63;
        const float* __restrict__ C = Cs[kp];
        float acc = 0.f;
        #pragma unroll
        for (int i = 0; i <= P; ++i) {
            const int u  = x - i;
            const int uc = u < 0 ? 0 : u;
            const float rv = (u >= 0) ? Rl[uc] : 0.f;
            acc = fmaf(C[i], rv, acc);
        }
        Rl[64 * kp + x] = acc;
    }
    __syncthreads();

    // publish base R[0..2048)
    #pragma unroll 1
    for (int j4 = tid; j4 < BASE / 4; j4 += K1_THREADS)
        reinterpret_cast<f4*>(R)[j4] = reinterpret_cast<const f4*>(Rl)[j4];
}

// ---------------------------------------------------------------------------
// Fused extension + output (R7 epilogue, verbatim form; BASE=2048 constants):
// tile [t0,t0+1024), k = t0>>11, tau0 = t0 & 2047 (0 or 1024):
//   R[2048k + tau0 + x] = win[64+x] + sum_i V_k[i]*win[64+x-i]
// Grid = 64 t-tiles x 32 batch-chunks = 2048 blocks.
// ---------------------------------------------------------------------------
__global__ __launch_bounds__(256) void ar_out_fused(const float* __restrict__ R,
                                                    const float* __restrict__ bias,
                                                    const float* __restrict__ noise,
                                                    float* __restrict__ out) {
    __shared__ __align__(16) float win[1088];   // R[tau0-64 .. tau0+1024)
    __shared__ __align__(16) float Vl[68];
    const int tid  = threadIdx.x;
    const int tile = blockIdx.x & 63;
    const int bc   = blockIdx.x >> 6;
    const int t0   = tile * W_TILE;
    const float b  = bias[0];
    const int k    = t0 >> 11;                  // 0..31
    const f4* __restrict__ Rg4 = reinterpret_cast<const f4*>(R);

    f4 rt;
    if (k == 0) {
        const f4 r = Rg4[(t0 >> 2) + tid];      // direct base path
        rt.x = b * r.x; rt.y = b * r.y; rt.z = b * r.z; rt.w = b * r.w;
    } else {
        const int tau0 = t0 & 2047;             // 0 or 1024
        if (tid < 65) Vl[tid] = R[VOFF + k * 80 + tid];
        f4* __restrict__ win4 = reinterpret_cast<f4*>(win);
        for (int j4 = tid; j4 < 272; j4 += 256) {
            const int u = tau0 - 64 + 4 * j4;   // multiple of 4
            f4 v;
            if (u >= 0) v = Rg4[u >> 2];
            else { v.x = 0.f; v.y = 0.f; v.z = 0.f; v.w = 0.f; }
            win4[j4] = v;
        }
        __syncthreads();
        const f4* __restrict__ V4 = reinterpret_cast<const f4*>(Vl);
        f4 w4[17];
        #pragma unroll
        for (int j = 0; j < 17; ++j) w4[j] = win4[tid + j];
        float a0 = w4[16].x, a1 = w4[16].y, a2 = w4[16].z, a3 = w4[16].w;
        #pragma unroll
        for (int g = 0; g < 16; ++g) {          // i = 4g..4g+3
            const f4 v  = V4[g];
            const f4 hi = w4[16 - g];
            const f4 lo = w4[15 - g];
            a0 = fmaf(v.x, hi.x, a0); a1 = fmaf(v.x, hi.y, a1);
            a2 = fmaf(v.x, hi.z, a2); a3 = fmaf(v.x, hi.w, a3);
            a0 = fmaf(v.y, lo.w, a0); a1 = fmaf(v.y, hi.x, a1);
            a2 = fmaf(v.y, hi.y, a2); a3 = fmaf(v.y, hi.z, a3);
            a0 = fmaf(v.z, lo.z, a0); a1 = fmaf(v.z, lo.w, a1);
            a2 = fmaf(v.z, hi.x, a2); a3 = fmaf(v.z, hi.y, a3);
            a0 = fmaf(v.w, lo.y, a0); a1 = fmaf(v.w, lo.z, a1);
            a2 = fmaf(v.w, lo.w, a2); a3 = fmaf(v.w, hi.x, a3);
        }
        const float v64 = Vl[64];
        a0 = fmaf(v64, w4[0].x, a0); a1 = fmaf(v64, w4[0].y, a1);
        a2 = fmaf(v64, w4[0].z, a2); a3 = fmaf(v64, w4[0].w, a3);
        rt.x = b * a0; rt.y = b * a1; rt.z = b * a2; rt.w = b * a3;
    }

    // stream 8 batch rows: 1 f4 column per thread, R tile in registers
    const int nb4 = T_LEN >> 2;
    const int col = (t0 >> 2) + tid;
    const f4* __restrict__ n4 = reinterpret_cast<const f4*>(noise);
    f4* __restrict__ o4 = reinterpret_cast<f4*>(out);
    #pragma unroll
    for (int bi = 0; bi < BCHUNK; ++bi) {
        const int idx = (bc * BCHUNK + bi) * nb4 + col;
        const f4 n = __builtin_nontemporal_load(n4 + idx);
        f4 o;
        o.x = fmaf(0.3f, n.x, rt.x);
        o.y = fmaf(0.3f, n.y, rt.y);
        o.z = fmaf(0.3f, n.z, rt.z);
        o.w = fmaf(0.3f, n.w, rt.w);
        __builtin_nontemporal_store(o, o4 + idx);
    }
}

extern "C" void kernel_launch(void* const* d_in, const int* in_sizes, int n_in,
                              void* d_out, int out_size, void* d_ws, size_t ws_size,
                              hipStream_t stream) {
    const float* params = (const float*)d_in[0];
    const float* bias   = (const float*)d_in[1];
    const float* noise  = (const float*)d_in[2];
    float* out = (float*)d_out;
    float* R   = (float*)d_ws;   // base R[0..2048) + V_1..31 at VOFF

    hipLaunchKernelGGL(ar_k1, dim3(1), dim3(K1_THREADS), 0, stream, params, R);
    hipLaunchKernelGGL(ar_out_fused, dim3(64 * 32), dim3(256), 0, stream,
                       R, bias, noise, out);
}

// Round 7
// 162.310 us; speedup vs baseline: 2.2774x; 1.5182x over previous
//
#include <hip/hip_runtime.h>

#define T_LEN   65536
#define P       64
#define BASE    4096           // base length produced by the in-block ladder
#define K1_THREADS 256
#define W_TILE  1024
#define BCHUNK  8
#define VOFF    65536          // V_k published at R[VOFF + 80*k .. +64], k=1..15

typedef float f4 __attribute__((ext_vector_type(4)));

// ---------------------------------------------------------------------------
// means[t] = bias * R[t], R = step response of the AR(64) filter:
//   R[t] = sum_k params[k]*R[t-1-k] + 1,  R[t<0] = 0
// Extension identity (valid for any tau in [0, L)):
//   R[L+tau] = R[tau] + sum_{i=0}^{64} V_L[i]*R[tau-i]
// R12: math identical to R7 (absmax-proven); the serialized stage COUNT of
// ar_k1 is halved. Cost model from R6..R11: ar_k1 ~ stages x per-stage
// latency (~0.65us/stage at idle-chip clock).
//   - fused tapV (R10-validated bit-exact): tap+reduce in ONE wave stage
//     -> ladder 3->2 barriers/level.
//   - the 14-step V tree has dependency depth 6 (widths 1,2,3,4,3,1): run
//     each level's nodes on DIFFERENT WAVES concurrently -> 42->12 barriers.
//   - base-R publish moved before the tree (global writes hide under it).
// ~66 stages -> ~28. Epilogue kernel is R7-verbatim.
// ---------------------------------------------------------------------------

// tree levels (same node defs as R7's sequential schedule):
// L0: 2=D(1,192)
// L1: 3=A(2,256) 4=D(2,128)
// L2: 6=D(3,192) 5=A(4,256) 8=D(4,64)
// L3: 7=A(6,256) 10=D(5,192) 12=D(6,128) 9=A(8,256)
// L4: 14=D(7,192) 11=A(10,256) 13=A(12,256)
// L5: 15=A(14,256)
__constant__ unsigned char  TL_DST[14] = {2, 3,4, 6,5,8, 7,10,12,9, 14,11,13, 15};
__constant__ unsigned char  TL_SRC[14] = {1, 2,2, 3,4,4, 6,5,6,8, 7,10,12, 14};
__constant__ unsigned char  TL_DBL[14] = {1, 0,1, 1,0,1, 0,1,1,0, 1,0,0, 0};
__constant__ unsigned short TL_W[14]   = {192, 256,128, 192,256,64, 256,192,128,256, 192,256,256, 256};
__constant__ unsigned char  TL_OFF[7]  = {0,1,3,6,10,13,14};

// Fused tap+reduce (R10-validated bit-exact vs R7's Wp form): lane j builds
// the four 16-wide partials of W0[j] in R7's order, sums left-assoc, then
// V[j] = W0[j]-W0[j-1] via shfl_up. Lane 63 writes V[64] = -W0[63].
__device__ __forceinline__ void tapV_wave(const float* __restrict__ td, int wd,
                                          const float* __restrict__ p,
                                          float* __restrict__ Vdst, int lane) {
    const int j = lane;
    float w0 = 0.f, w1 = 0.f, w2 = 0.f, w3 = 0.f;
    #pragma unroll
    for (int mm = 0; mm < 16; ++mm) w0 = fmaf(p[mm + j],      td[wd - 1  - mm], w0);
    #pragma unroll
    for (int mm = 0; mm < 16; ++mm) w1 = fmaf(p[16 + mm + j], td[wd - 17 - mm], w1);
    #pragma unroll
    for (int mm = 0; mm < 16; ++mm) w2 = fmaf(p[32 + mm + j], td[wd - 33 - mm], w2);
    #pragma unroll
    for (int mm = 0; mm < 16; ++mm) w3 = fmaf(p[48 + mm + j], td[wd - 49 - mm], w3);
    const float wj  = ((w0 + w1) + w2) + w3;
    const float wm1 = __shfl_up(wj, 1);
    Vdst[j] = (j == 0) ? wj : (wj - wm1);
    if (j == 63) Vdst[64] = 0.0f - wj;
}

__global__ __launch_bounds__(K1_THREADS, 1) void ar_k1(const float* __restrict__ params,
                                                       float* __restrict__ R) {
    __shared__ __align__(16) float Rl[BASE];
    __shared__ float p[128];          // zero-padded: p[64..127] = 0 masks m+j>63
    __shared__ __align__(16) float Vs[68];
    __shared__ __align__(16) float Vnode[16][68];   // V_k, k=1..15
    __shared__ __align__(16) float Tn[8][256];      // kept tails, nodes 2..7
    __shared__ __align__(16) float Tw[4][256];      // transient tails (per wave)
    const int tid = threadIdx.x;
    if (tid < 128) p[tid] = (tid < P) ? params[tid] : 0.f;
    __syncthreads();

    // ---- serial stage: lane t holds transposed-form state (verbatim) ----
    if (tid < 64) {
        float z = 0.f;
        const float pk = p[tid];
        #pragma unroll 1
        for (int t = 0; t < 64; ++t) {
            float y  = __shfl(z, 0) + 1.0f;   // R[t]
            float zn = __shfl_down(z, 1);
            if (tid == 63) zn = 0.f;
            z = fmaf(pk, y, zn);
            if (tid == 0) Rl[t] = y;
        }
    }
    __syncthreads();

    // ---- ladder 64 -> 4096 in LDS: 2 stages/level (fused tapV, then
    //      boundary + blocked conv — R10-validated bit-exact pipeline) ----
    #pragma unroll 1
    for (int L = 64; L <= BASE / 2; L <<= 1) {
        if (tid < 64) tapV_wave(Rl, L, p, Vs, tid);
        __syncthreads();
        if (tid < P) {                          // boundary tau in [0,64)
            const int tau = tid;
            float acc = Rl[tau];
            #pragma unroll
            for (int i = 0; i < P; ++i) {
                const int idx = (tau - i) > 0 ? (tau - i) : 0;
                const float v = (i <= tau) ? Vs[i] : 0.f;
                acc = fmaf(v, Rl[idx], acc);
            }
            Rl[L + tau] = acc;
        }
        {                                       // blocked tau in [64,L)
            const f4* __restrict__ Rl4 = reinterpret_cast<const f4*>(Rl);
            f4* __restrict__ Rl4w = reinterpret_cast<f4*>(Rl);
            const f4* __restrict__ V4 = reinterpret_cast<const f4*>(Vs);
            const int nq = (L - 64) >> 2;
            #pragma unroll 1
            for (int q = tid; q < nq; q += K1_THREADS) {
                f4 w4[17];
                #pragma unroll
                for (int j = 0; j < 17; ++j) w4[j] = Rl4[q + j];
                float a0 = w4[16].x, a1 = w4[16].y, a2 = w4[16].z, a3 = w4[16].w;
                #pragma unroll
                for (int g = 0; g < 16; ++g) {   // i = 4g..4g+3
                    const f4 v  = V4[g];
                    const f4 hi = w4[16 - g];
                    const f4 lo = w4[15 - g];
                    a0 = fmaf(v.x, hi.x, a0); a1 = fmaf(v.x, hi.y, a1);
                    a2 = fmaf(v.x, hi.z, a2); a3 = fmaf(v.x, hi.w, a3);
                    a0 = fmaf(v.y, lo.w, a0); a1 = fmaf(v.y, hi.x, a1);
                    a2 = fmaf(v.y, hi.y, a2); a3 = fmaf(v.y, hi.z, a3);
                    a0 = fmaf(v.z, lo.z, a0); a1 = fmaf(v.z, lo.w, a1);
                    a2 = fmaf(v.z, hi.x, a2); a3 = fmaf(v.z, hi.y, a3);
                    a0 = fmaf(v.w, lo.y, a0); a1 = fmaf(v.w, lo.z, a1);
                    a2 = fmaf(v.w, lo.w, a2); a3 = fmaf(v.w, hi.x, a3);
                }
                const float v64 = Vs[64];
                a0 = fmaf(v64, w4[0].x, a0); a1 = fmaf(v64, w4[0].y, a1);
                a2 = fmaf(v64, w4[0].z, a2); a3 = fmaf(v64, w4[0].w, a3);
                f4 o; o.x = a0; o.y = a1; o.z = a2; o.w = a3;
                Rl4w[((L + 64) >> 2) + q] = o;
            }
        }
        __syncthreads();
    }

    // ---- publish base R[0..4096) NOW (write latency hides under the tree;
    //      Rl is read-only from here on) ----
    #pragma unroll 1
    for (int j4 = tid; j4 < BASE / 4; j4 += K1_THREADS)
        reinterpret_cast<f4*>(R)[j4] = reinterpret_cast<const f4*>(Rl)[j4];

    // ---- node 1 tap: V_4096 from the base tail R[3840..4096) ----
    if (tid < 64) tapV_wave(Rl + 3840, 256, p, Vnode[1], tid);
    __syncthreads();

    // ---- wave-parallel tree: 6 levels, nodes of a level on distinct waves.
    //      Per-element arithmetic identical to R7's sequential steps. ----
    #pragma unroll 1
    for (int lvl = 0; lvl < 6; ++lvl) {
        const int w = tid >> 6, lane = tid & 63;
        const int n0 = TL_OFF[lvl], n1 = TL_OFF[lvl + 1];
        const int e = n0 + w;
        float* td = nullptr;
        int wd = 0;
        if (e < n1) {
            const int dst = TL_DST[e], src = TL_SRC[e];
            wd = TL_W[e];
            const float* __restrict__ Vsr = Vnode[src];
            const float* tail = (src == 1) ? (Rl + 3840) : Tn[src];
            const float* s0 = TL_DBL[e] ? (tail + 64) : (Rl + 3840);
            td = (dst <= 7) ? Tn[dst] : Tw[w];
            #pragma unroll 1
            for (int x = lane; x < wd; x += 64) {
                float acc = s0[x];
                #pragma unroll
                for (int i = 0; i <= P; ++i)
                    acc = fmaf(Vsr[i], s0[x - i], acc);
                td[x] = acc;
            }
        }
        __syncthreads();
        if (e < n1) tapV_wave(td, wd, p, Vnode[TL_DST[e]], lane);
        __syncthreads();
    }

    // ---- publish V_1..V_15 ----
    #pragma unroll 1
    for (int j = tid; j < 15 * 80; j += K1_THREADS) {
        const int k = j / 80 + 1, i = j - (k - 1) * 80;
        if (i < 65) R[VOFF + k * 80 + i] = Vnode[k][i];
    }
}

// ---------------------------------------------------------------------------
// Fused extension + output (R7 ar_out, verbatim): tile [t0, t0+1024) with
// k = t0>>12, tau0 = t0&4095: R[t] = win[64+x] + sum_i V_k[i]*win[64+x-i],
// conv result stays in streaming registers. Grid = 64 x 32 = 2048 blocks.
// ---------------------------------------------------------------------------
__global__ __launch_bounds__(256) void ar_out_fused(const float* __restrict__ R,
                                                    const float* __restrict__ bias,
                                                    const float* __restrict__ noise,
                                                    float* __restrict__ out) {
    __shared__ __align__(16) float win[1088];   // R[tau0-64 .. tau0+1024)
    __shared__ __align__(16) float Vl[68];
    const int tid  = threadIdx.x;
    const int tile = blockIdx.x & 63;
    const int bc   = blockIdx.x >> 6;
    const int t0   = tile * W_TILE;
    const float b  = bias[0];
    const int k    = t0 >> 12;                  // 0..15
    const f4* __restrict__ Rg4 = reinterpret_cast<const f4*>(R);

    f4 rt;
    if (k == 0) {
        const f4 r = Rg4[(t0 >> 2) + tid];      // bitwise-identical base path
        rt.x = b * r.x; rt.y = b * r.y; rt.z = b * r.z; rt.w = b * r.w;
    } else {
        const int tau0 = t0 & 4095;
        if (tid < 65) Vl[tid] = R[VOFF + k * 80 + tid];
        f4* __restrict__ win4 = reinterpret_cast<f4*>(win);
        for (int j4 = tid; j4 < 272; j4 += 256) {
            const int u = tau0 - 64 + 4 * j4;   // multiple of 4
            f4 v;
            if (u >= 0) v = Rg4[u >> 2];
            else { v.x = 0.f; v.y = 0.f; v.z = 0.f; v.w = 0.f; }
            win4[j4] = v;
        }
        __syncthreads();
        // 65-tap conv, f4-blocked (same index algebra as the ladder's loop)
        const f4* __restrict__ V4 = reinterpret_cast<const f4*>(Vl);
        f4 w4[17];
        #pragma unroll
        for (int j = 0; j < 17; ++j) w4[j] = win4[tid + j];
        float a0 = w4[16].x, a1 = w4[16].y, a2 = w4[16].z, a3 = w4[16].w;
        #pragma unroll
        for (int g = 0; g < 16; ++g) {
            const f4 v  = V4[g];
            const f4 hi = w4[16 - g];
            const f4 lo = w4[15 - g];
            a0 = fmaf(v.x, hi.x, a0); a1 = fmaf(v.x, hi.y, a1);
            a2 = fmaf(v.x, hi.z, a2); a3 = fmaf(v.x, hi.w, a3);
            a0 = fmaf(v.y, lo.w, a0); a1 = fmaf(v.y, hi.x, a1);
            a2 = fmaf(v.y, hi.y, a2); a3 = fmaf(v.y, hi.z, a3);
            a0 = fmaf(v.z, lo.z, a0); a1 = fmaf(v.z, lo.w, a1);
            a2 = fmaf(v.z, hi.x, a2); a3 = fmaf(v.z, hi.y, a3);
            a0 = fmaf(v.w, lo.y, a0); a1 = fmaf(v.w, lo.z, a1);
            a2 = fmaf(v.w, lo.w, a2); a3 = fmaf(v.w, hi.x, a3);
        }
        const float v64 = Vl[64];
        a0 = fmaf(v64, w4[0].x, a0); a1 = fmaf(v64, w4[0].y, a1);
        a2 = fmaf(v64, w4[0].z, a2); a3 = fmaf(v64, w4[0].w, a3);
        rt.x = b * a0; rt.y = b * a1; rt.z = b * a2; rt.w = b * a3;
    }

    // stream 8 batch rows: 1 f4 column per thread, R tile in registers
    const int nb4 = T_LEN >> 2;
    const int col = (t0 >> 2) + tid;
    const f4* __restrict__ n4 = reinterpret_cast<const f4*>(noise);
    f4* __restrict__ o4 = reinterpret_cast<f4*>(out);
    #pragma unroll
    for (int bi = 0; bi < BCHUNK; ++bi) {
        const int idx = (bc * BCHUNK + bi) * nb4 + col;
        const f4 n = __builtin_nontemporal_load(n4 + idx);
        f4 o;
        o.x = fmaf(0.3f, n.x, rt.x);
        o.y = fmaf(0.3f, n.y, rt.y);
        o.z = fmaf(0.3f, n.z, rt.z);
        o.w = fmaf(0.3f, n.w, rt.w);
        __builtin_nontemporal_store(o, o4 + idx);
    }
}

extern "C" void kernel_launch(void* const* d_in, const int* in_sizes, int n_in,
                              void* d_out, int out_size, void* d_ws, size_t ws_size,
                              hipStream_t stream) {
    const float* params = (const float*)d_in[0];
    const float* bias   = (const float*)d_in[1];
    const float* noise  = (const float*)d_in[2];
    float* out = (float*)d_out;
    float* R   = (float*)d_ws;   // base R[0..4096) + V_1..15 at VOFF

    hipLaunchKernelGGL(ar_k1, dim3(1), dim3(K1_THREADS), 0, stream, params, R);
    hipLaunchKernelGGL(ar_out_fused, dim3(64 * 32), dim3(256), 0, stream,
                       R, bias, noise, out);
}